// Round 4
// baseline (134.601 us; speedup 1.0000x reference)
//
#include <hip/hip_runtime.h>

#define NB 8
#define NN 4096
#define NS 1024
#define NC 64
#define OUT_PTS_OFF (NB*NS*3)
#define CAP 512
#define RB 0.2f

typedef __attribute__((ext_vector_type(8))) short bf16x8;
typedef __attribute__((ext_vector_type(4))) float f32x4;

static __device__ __forceinline__ short f2bf(float f){
  unsigned u = __float_as_uint(f);
  unsigned r = (u + 0x7FFFu + ((u>>16)&1u)) >> 16;
  return (short)r;
}
static __device__ __forceinline__ float bf2f(short s){
  return __uint_as_float(((unsigned)(unsigned short)s) << 16);
}

// ws layout:
//   int   gsidx[8192][64]            @ byte 0        (2 MB)
//   short px1  [32768][64]           @ byte 2097152  (4 MB)
//   short wf   [47104]               @ byte 6291456  (94 KB)
//     wf0 [3][4][64][8] @0 ; wf1 [2][8][64][8] @6144 ; wf2 [4][16][64][8] @14336
#define WS_PX1_SH   1048576
#define WS_WF_SH    3145728

__global__ __launch_bounds__(256) void prep_weights(
    const float* __restrict__ w0, const float* __restrict__ w1,
    const float* __restrict__ w2, short* __restrict__ ws)
{
  int e = blockIdx.x*256 + threadIdx.x;
  if (e >= 47104) return;
  float v = 0.f;
  if (e < 6144) {
    int j=e&7, l=(e>>3)&63, nt=(e>>9)&3, kt=e>>11;
    int k = kt*32 + ((l>>4)<<3) + j, n = nt*16 + (l&15);
    if (k < 64) v = w0[(3+k)*64 + n];
    else if (k < 67) v = w0[(k-64)*64 + n];
  } else if (e < 14336) {
    int e2=e-6144;
    int j=e2&7, l=(e2>>3)&63, nt=(e2>>9)&7, kt=e2>>12;
    int k = kt*32 + ((l>>4)<<3) + j, n = nt*16 + (l&15);
    v = w1[k*128 + n];
  } else {
    int e3=e-14336;
    int j=e3&7, l=(e3>>3)&63, nt=(e3>>9)&15, kt=e3>>13;
    int k = kt*32 + ((l>>4)<<3) + j, n = nt*16 + (l&15);
    v = w2[k*256 + n];
  }
  ws[e] = f2bf(v);
}

// ---- PX1[b,n,f] = ([points, xyz] @ w0_perm)[b,n,f]   (bf16, NO relu) ----
__global__ __launch_bounds__(256) void px1_kernel(
    const float* __restrict__ xyz, const float* __restrict__ points,
    const short* __restrict__ wsb, short* __restrict__ px1)
{
  const int tid = threadIdx.x;
  const int w = tid>>6, l = tid&63, lr = l&15, grp = l>>4;
  const int rowbase = blockIdx.x*64 + w*16;
  const int row = rowbase + lr;
  const float* prow = points + (size_t)row*NC;
  const float* xr   = xyz + (size_t)row*3;

  bf16x8 a0, a1, a2;
  {
    float4 u0 = *(const float4*)(prow + grp*8);
    float4 u1 = *(const float4*)(prow + grp*8 + 4);
    float4 u2 = *(const float4*)(prow + 32 + grp*8);
    float4 u3 = *(const float4*)(prow + 32 + grp*8 + 4);
    a0 = (bf16x8){f2bf(u0.x),f2bf(u0.y),f2bf(u0.z),f2bf(u0.w),f2bf(u1.x),f2bf(u1.y),f2bf(u1.z),f2bf(u1.w)};
    a1 = (bf16x8){f2bf(u2.x),f2bf(u2.y),f2bf(u2.z),f2bf(u2.w),f2bf(u3.x),f2bf(u3.y),f2bf(u3.z),f2bf(u3.w)};
    short e0=0,e1=0,e2v=0;
    if (grp==0) { e0=f2bf(xr[0]); e1=f2bf(xr[1]); e2v=f2bf(xr[2]); }
    a2 = (bf16x8){e0,e1,e2v,0,0,0,0,0};
  }
  f32x4 zero4 = {0.f,0.f,0.f,0.f};
  #pragma unroll
  for (int nt=0; nt<4; ++nt) {
    f32x4 acc = zero4;
    bf16x8 b0 = *(const bf16x8*)(wsb + (((0*4+nt)*64 + l)<<3));
    bf16x8 b1 = *(const bf16x8*)(wsb + (((1*4+nt)*64 + l)<<3));
    bf16x8 b2 = *(const bf16x8*)(wsb + (((2*4+nt)*64 + l)<<3));
    acc = __builtin_amdgcn_mfma_f32_16x16x32_bf16(a0, b0, acc, 0,0,0);
    acc = __builtin_amdgcn_mfma_f32_16x16x32_bf16(a1, b1, acc, 0,0,0);
    acc = __builtin_amdgcn_mfma_f32_16x16x32_bf16(a2, b2, acc, 0,0,0);
    #pragma unroll
    for (int i=0;i<4;++i)
      px1[(size_t)(rowbase + grp*4 + i)*64 + nt*16 + lr] = f2bf(acc[i]);
  }
}

// ---- selection: exact query_ball_point semantics, writes gsidx + new_xyz ----
__global__ __launch_bounds__(256) void select_kernel(
    const float* __restrict__ xyz, const int* __restrict__ fps_inds,
    int* __restrict__ gsidx, float* __restrict__ out)
{
  __shared__ unsigned int cand_d[CAP];
  __shared__ int cand_i[CAP];
  __shared__ int scnt[256];
  __shared__ int chunkbase[64];
  __shared__ int tmp64[64];
  __shared__ int sc0;

  const int q = blockIdx.x, b = q >> 10, tid = threadIdx.x;
  const float* xb = xyz + (size_t)b*NN*3;
  const int fps = fps_inds[q];
  const float qx = xb[fps*3+0], qy = xb[fps*3+1], qz = xb[fps*3+2];
  if (tid < 3) out[q*3+tid] = xb[fps*3+tid];

  unsigned int dbits[16]; unsigned int msk=0; int c=0;
  {
    const float4* xv = (const float4*)(xb + tid*48);
    #pragma unroll
    for (int g=0; g<4; ++g) {
      float4 v0 = xv[g*3], v1 = xv[g*3+1], v2 = xv[g*3+2];
      float px[4] = {v0.x, v0.w, v1.z, v2.y};
      float py[4] = {v0.y, v1.x, v1.w, v2.z};
      float pz[4] = {v0.z, v1.y, v2.x, v2.w};
      #pragma unroll
      for (int u=0; u<4; ++u) {
        float dx=__fsub_rn(qx,px[u]), dy=__fsub_rn(qy,py[u]), dz=__fsub_rn(qz,pz[u]);
        float d2=__fadd_rn(__fadd_rn(__fmul_rn(dx,dx),__fmul_rn(dy,dy)),__fmul_rn(dz,dz));
        float d = __fsqrt_rn(d2);
        dbits[g*4+u] = __float_as_uint(d);
        if (d < RB) { msk |= 1u<<(g*4+u); c++; }
      }
    }
  }
  scnt[tid] = c; __syncthreads();
  if (tid < 64) {
    int s = scnt[tid*4]+scnt[tid*4+1]+scnt[tid*4+2]+scnt[tid*4+3];
    int incl = s;
    #pragma unroll
    for (int off=1; off<64; off<<=1) {
      int vv = __shfl_up(incl, off, 64);
      if (tid >= off) incl += vv;
    }
    chunkbase[tid] = incl - s;
    if (tid == 63) sc0 = incl;
  }
  __syncthreads();
  int cnt = sc0; if (cnt > CAP) cnt = CAP;
  {
    int base = chunkbase[tid>>2];
    for (int u = (tid & ~3); u < tid; ++u) base += scnt[u];
    #pragma unroll
    for (int r=0; r<16; ++r) {
      if (msk & (1u<<r)) {
        if (base < CAP) { cand_d[base] = dbits[r]; cand_i[base] = tid*16+r; }
        base++;
      }
    }
  }
  __syncthreads();

  if (cnt > 64) {
    for (int j=tid; j<cnt; j+=256) {
      unsigned dj = cand_d[j]; int rk=0;
      for (int i=0;i<cnt;++i) { unsigned di=cand_d[i]; rk += (int)((di<dj) | ((di==dj) & (i<j))); }
      if (rk < 64) tmp64[rk] = cand_i[j];
    }
    __syncthreads();
    if (tid < 64) {
      int v = tmp64[tid]; int p=0;
      for (int u=0;u<64;++u) p += (tmp64[u] < v);
      gsidx[q*64 + p] = v;
    }
  } else {
    if (tid < 64) gsidx[q*64 + tid] = cand_i[tid < cnt ? tid : 0];
  }
}

// ---- MLP: 2 queries/block, layer-3 B prefetched to registers ----
__global__ __launch_bounds__(512,2) void mlp_kernel(
    const float* __restrict__ xyz, const int* __restrict__ fps_inds,
    const float* __restrict__ w0, const short* __restrict__ wsb,
    const short* __restrict__ px1, const int* __restrict__ gsidx,
    float* __restrict__ out)
{
  __shared__ short h2[2][64][136];   // 34816 B
  __shared__ float q1s[2][64];
  __shared__ int sidx[2][64];

  const int tid = threadIdx.x;
  const int w = tid>>6, l = tid&63, lr = l&15, grp = l>>4;
  const int qsel = w>>2, wl = w&3;
  const int q = blockIdx.x*2 + qsel, b = q >> 10;

  // ---- prefetch ALL layer-3 B fragments for this wave's 4 ntiles (64 VGPR) ----
  bf16x8 b3[4][4];
  #pragma unroll
  for (int kt=0; kt<4; ++kt)
    #pragma unroll
    for (int j=0; j<4; ++j)
      b3[kt][j] = *(const bf16x8*)(wsb + 14336 + (((kt*16 + wl*4 + j)*64 + l)<<3));

  if (tid < 128) {
    int qq = tid>>6, t = tid&63;
    int qg = blockIdx.x*2 + qq;
    int bb = qg >> 10;
    const float* xb = xyz + (size_t)bb*NN*3;
    int fp = fps_inds[qg];
    float qx = xb[fp*3+0], qy = xb[fp*3+1], qz = xb[fp*3+2];
    q1s[qq][t] = qx*w0[t] + qy*w0[64+t] + qz*w0[128+t];
    sidx[qq][t] = gsidx[qg*64 + t];
  }
  __syncthreads();

  const int myrow = wl*16 + lr;
  const int idx = sidx[qsel][myrow];
  const short* pr = px1 + (size_t)(b*NN + idx)*64;

  f32x4 zero4 = {0.f,0.f,0.f,0.f};

  // h1 = relu(PX1[idx] - Q1), built in registers
  bf16x8 a20, a21;
  {
    bf16x8 v0 = *(const bf16x8*)(pr + grp*8);
    bf16x8 v1 = *(const bf16x8*)(pr + 32 + grp*8);
    #pragma unroll
    for (int j=0;j<8;++j) {
      a20[j] = f2bf(fmaxf(bf2f(v0[j]) - q1s[qsel][grp*8+j], 0.f));
      a21[j] = f2bf(fmaxf(bf2f(v1[j]) - q1s[qsel][32+grp*8+j], 0.f));
    }
  }

  // layer 2: 16x64 @ 64x128, wave-private rows
  #pragma unroll
  for (int nt=0; nt<8; ++nt) {
    f32x4 acc = zero4;
    bf16x8 b0 = *(const bf16x8*)(wsb + 6144 + (((0*8+nt)*64 + l)<<3));
    bf16x8 b1 = *(const bf16x8*)(wsb + 6144 + (((1*8+nt)*64 + l)<<3));
    acc = __builtin_amdgcn_mfma_f32_16x16x32_bf16(a20, b0, acc, 0,0,0);
    acc = __builtin_amdgcn_mfma_f32_16x16x32_bf16(a21, b1, acc, 0,0,0);
    #pragma unroll
    for (int i=0;i<4;++i)
      h2[qsel][wl*16 + grp*4 + i][nt*16 + lr] = f2bf(fmaxf(acc[i], 0.f));
  }
  __syncthreads();

  // layer 3: wave owns ntiles wl*4..wl*4+3 of its query; B from regs, A from LDS
  #pragma unroll
  for (int pair=0; pair<2; ++pair) {
    f32x4 acc[4][2];
    #pragma unroll
    for (int mt=0; mt<4; ++mt) { acc[mt][0]=zero4; acc[mt][1]=zero4; }
    #pragma unroll
    for (int kt=0; kt<4; ++kt) {
      #pragma unroll
      for (int mt=0; mt<4; ++mt) {
        bf16x8 a = *(const bf16x8*)&h2[qsel][mt*16 + lr][kt*32 + grp*8];
        acc[mt][0] = __builtin_amdgcn_mfma_f32_16x16x32_bf16(a, b3[kt][pair*2+0], acc[mt][0], 0,0,0);
        acc[mt][1] = __builtin_amdgcn_mfma_f32_16x16x32_bf16(a, b3[kt][pair*2+1], acc[mt][1], 0,0,0);
      }
    }
    #pragma unroll
    for (int n2=0; n2<2; ++n2) {
      float m = 0.f;
      #pragma unroll
      for (int mt=0; mt<4; ++mt)
        #pragma unroll
        for (int i=0; i<4; ++i) m = fmaxf(m, acc[mt][n2][i]);
      m = fmaxf(m, __shfl_xor(m, 16, 64));
      m = fmaxf(m, __shfl_xor(m, 32, 64));
      if (grp == 0) out[OUT_PTS_OFF + q*256 + (wl*4 + pair*2 + n2)*16 + lr] = m;
    }
  }
}

extern "C" void kernel_launch(void* const* d_in, const int* in_sizes, int n_in,
                              void* d_out, int out_size, void* d_ws, size_t ws_size,
                              hipStream_t stream) {
  const float* xyz      = (const float*)d_in[0];
  const float* points   = (const float*)d_in[1];
  const int*   fps_inds = (const int*)d_in[2];
  const float* w0       = (const float*)d_in[3];
  const float* w1       = (const float*)d_in[4];
  const float* w2       = (const float*)d_in[5];
  float* out = (float*)d_out;

  int*   gsidx = (int*)d_ws;
  short* px1   = (short*)d_ws + WS_PX1_SH;
  short* wsb   = (short*)d_ws + WS_WF_SH;

  hipLaunchKernelGGL(prep_weights, dim3(184), dim3(256), 0, stream, w0, w1, w2, wsb);
  hipLaunchKernelGGL(px1_kernel,   dim3(512), dim3(256), 0, stream, xyz, points, wsb, px1);
  hipLaunchKernelGGL(select_kernel,dim3(NB*NS), dim3(256), 0, stream, xyz, fps_inds, gsidx, out);
  hipLaunchKernelGGL(mlp_kernel,   dim3(NB*NS/2), dim3(512), 0, stream,
                     xyz, fps_inds, w0, wsb, px1, gsidx, out);
}

// Round 5
// 110.810 us; speedup vs baseline: 1.2147x; 1.2147x over previous
//
#include <hip/hip_runtime.h>

#define NB 8
#define NN 4096
#define NS 1024
#define NC 64
#define OUT_PTS_OFF (NB*NS*3)
#define CAP 512
#define RB 0.2f
#define QPB 8

typedef __attribute__((ext_vector_type(8))) short bf16x8;
typedef __attribute__((ext_vector_type(4))) float f32x4;

static __device__ __forceinline__ short f2bf(float f){
  unsigned u = __float_as_uint(f);
  unsigned r = (u + 0x7FFFu + ((u>>16)&1u)) >> 16;
  return (short)r;
}
static __device__ __forceinline__ float bf2f(short s){
  return __uint_as_float(((unsigned)(unsigned short)s) << 16);
}

// ws layout:
//   int   gsidx[8192][64]            @ byte 0        (2 MB)
//   short px1  [32768][64]           @ byte 2097152  (4 MB)
//   short wf   [47104]               @ byte 6291456  (94 KB)
//     wf0 [3][4][64][8] @0 ; wf1 [2][8][64][8] @6144 ; wf2 [4][16][64][8] @14336
#define WS_PX1_SH   1048576
#define WS_WF_SH    3145728

__global__ __launch_bounds__(256) void prep_weights(
    const float* __restrict__ w0, const float* __restrict__ w1,
    const float* __restrict__ w2, short* __restrict__ ws)
{
  int e = blockIdx.x*256 + threadIdx.x;
  if (e >= 47104) return;
  float v = 0.f;
  if (e < 6144) {
    int j=e&7, l=(e>>3)&63, nt=(e>>9)&3, kt=e>>11;
    int k = kt*32 + ((l>>4)<<3) + j, n = nt*16 + (l&15);
    if (k < 64) v = w0[(3+k)*64 + n];
    else if (k < 67) v = w0[(k-64)*64 + n];
  } else if (e < 14336) {
    int e2=e-6144;
    int j=e2&7, l=(e2>>3)&63, nt=(e2>>9)&7, kt=e2>>12;
    int k = kt*32 + ((l>>4)<<3) + j, n = nt*16 + (l&15);
    v = w1[k*128 + n];
  } else {
    int e3=e-14336;
    int j=e3&7, l=(e3>>3)&63, nt=(e3>>9)&15, kt=e3>>13;
    int k = kt*32 + ((l>>4)<<3) + j, n = nt*16 + (l&15);
    v = w2[k*256 + n];
  }
  ws[e] = f2bf(v);
}

// ---- PX1[b,n,f] = ([points, xyz] @ w0_perm)[b,n,f]   (bf16, NO relu) ----
__global__ __launch_bounds__(256) void px1_kernel(
    const float* __restrict__ xyz, const float* __restrict__ points,
    const short* __restrict__ wsb, short* __restrict__ px1)
{
  const int tid = threadIdx.x;
  const int w = tid>>6, l = tid&63, lr = l&15, grp = l>>4;
  const int rowbase = blockIdx.x*64 + w*16;
  const int row = rowbase + lr;
  const float* prow = points + (size_t)row*NC;
  const float* xr   = xyz + (size_t)row*3;

  bf16x8 a0, a1, a2;
  {
    float4 u0 = *(const float4*)(prow + grp*8);
    float4 u1 = *(const float4*)(prow + grp*8 + 4);
    float4 u2 = *(const float4*)(prow + 32 + grp*8);
    float4 u3 = *(const float4*)(prow + 32 + grp*8 + 4);
    a0 = (bf16x8){f2bf(u0.x),f2bf(u0.y),f2bf(u0.z),f2bf(u0.w),f2bf(u1.x),f2bf(u1.y),f2bf(u1.z),f2bf(u1.w)};
    a1 = (bf16x8){f2bf(u2.x),f2bf(u2.y),f2bf(u2.z),f2bf(u2.w),f2bf(u3.x),f2bf(u3.y),f2bf(u3.z),f2bf(u3.w)};
    short e0=0,e1=0,e2v=0;
    if (grp==0) { e0=f2bf(xr[0]); e1=f2bf(xr[1]); e2v=f2bf(xr[2]); }
    a2 = (bf16x8){e0,e1,e2v,0,0,0,0,0};
  }
  f32x4 zero4 = {0.f,0.f,0.f,0.f};
  #pragma unroll
  for (int nt=0; nt<4; ++nt) {
    f32x4 acc = zero4;
    bf16x8 b0 = *(const bf16x8*)(wsb + (((0*4+nt)*64 + l)<<3));
    bf16x8 b1 = *(const bf16x8*)(wsb + (((1*4+nt)*64 + l)<<3));
    bf16x8 b2 = *(const bf16x8*)(wsb + (((2*4+nt)*64 + l)<<3));
    acc = __builtin_amdgcn_mfma_f32_16x16x32_bf16(a0, b0, acc, 0,0,0);
    acc = __builtin_amdgcn_mfma_f32_16x16x32_bf16(a1, b1, acc, 0,0,0);
    acc = __builtin_amdgcn_mfma_f32_16x16x32_bf16(a2, b2, acc, 0,0,0);
    #pragma unroll
    for (int i=0;i<4;++i)
      px1[(size_t)(rowbase + grp*4 + i)*64 + nt*16 + lr] = f2bf(acc[i]);
  }
}

// ---- selection: exact query_ball_point semantics, writes gsidx + new_xyz ----
__global__ __launch_bounds__(256) void select_kernel(
    const float* __restrict__ xyz, const int* __restrict__ fps_inds,
    int* __restrict__ gsidx, float* __restrict__ out)
{
  __shared__ unsigned int cand_d[CAP];
  __shared__ int cand_i[CAP];
  __shared__ int scnt[256];
  __shared__ int chunkbase[64];
  __shared__ int tmp64[64];
  __shared__ int sc0;

  const int q = blockIdx.x, b = q >> 10, tid = threadIdx.x;
  const float* xb = xyz + (size_t)b*NN*3;
  const int fps = fps_inds[q];
  const float qx = xb[fps*3+0], qy = xb[fps*3+1], qz = xb[fps*3+2];
  if (tid < 3) out[q*3+tid] = xb[fps*3+tid];

  unsigned int dbits[16]; unsigned int msk=0; int c=0;
  {
    const float4* xv = (const float4*)(xb + tid*48);
    #pragma unroll
    for (int g=0; g<4; ++g) {
      float4 v0 = xv[g*3], v1 = xv[g*3+1], v2 = xv[g*3+2];
      float px[4] = {v0.x, v0.w, v1.z, v2.y};
      float py[4] = {v0.y, v1.x, v1.w, v2.z};
      float pz[4] = {v0.z, v1.y, v2.x, v2.w};
      #pragma unroll
      for (int u=0; u<4; ++u) {
        float dx=__fsub_rn(qx,px[u]), dy=__fsub_rn(qy,py[u]), dz=__fsub_rn(qz,pz[u]);
        float d2=__fadd_rn(__fadd_rn(__fmul_rn(dx,dx),__fmul_rn(dy,dy)),__fmul_rn(dz,dz));
        float d = __fsqrt_rn(d2);
        dbits[g*4+u] = __float_as_uint(d);
        if (d < RB) { msk |= 1u<<(g*4+u); c++; }
      }
    }
  }
  scnt[tid] = c; __syncthreads();
  if (tid < 64) {
    int s = scnt[tid*4]+scnt[tid*4+1]+scnt[tid*4+2]+scnt[tid*4+3];
    int incl = s;
    #pragma unroll
    for (int off=1; off<64; off<<=1) {
      int vv = __shfl_up(incl, off, 64);
      if (tid >= off) incl += vv;
    }
    chunkbase[tid] = incl - s;
    if (tid == 63) sc0 = incl;
  }
  __syncthreads();
  int cnt = sc0; if (cnt > CAP) cnt = CAP;
  {
    int base = chunkbase[tid>>2];
    for (int u = (tid & ~3); u < tid; ++u) base += scnt[u];
    #pragma unroll
    for (int r=0; r<16; ++r) {
      if (msk & (1u<<r)) {
        if (base < CAP) { cand_d[base] = dbits[r]; cand_i[base] = tid*16+r; }
        base++;
      }
    }
  }
  __syncthreads();

  if (cnt > 64) {
    for (int j=tid; j<cnt; j+=256) {
      unsigned dj = cand_d[j]; int rk=0;
      for (int i=0;i<cnt;++i) { unsigned di=cand_d[i]; rk += (int)((di<dj) | ((di==dj) & (i<j))); }
      if (rk < 64) tmp64[rk] = cand_i[j];
    }
    __syncthreads();
    if (tid < 64) {
      int v = tmp64[tid]; int p=0;
      for (int u=0;u<64;++u) p += (tmp64[u] < v);
      gsidx[q*64 + p] = v;
    }
  } else {
    if (tid < 64) gsidx[q*64 + tid] = cand_i[tid < cnt ? tid : 0];
  }
}

// ---- MLP: persistent block, QPB queries/block, wf2 frags hoisted to regs ----
__global__ __launch_bounds__(256,2) void mlp_kernel(
    const float* __restrict__ xyz, const int* __restrict__ fps_inds,
    const float* __restrict__ w0, const short* __restrict__ wsb,
    const short* __restrict__ px1, const int* __restrict__ gsidx,
    float* __restrict__ out)
{
  __shared__ short h2[2][64][136];   // double-buffered, 34816 B
  __shared__ float q1s[QPB][64];
  __shared__ int sidx[QPB][64];

  const int tid = threadIdx.x;
  const int w = tid>>6, l = tid&63, lr = l&15, grp = l>>4;
  const int q0 = blockIdx.x*QPB;     // 1024 % QPB == 0: block never straddles batch
  const int b = q0 >> 10;
  const float* xb = xyz + (size_t)b*NN*3;

  // ---- loop-invariant: layer-3 B frags for this wave's 4 ntiles (64 VGPR) ----
  bf16x8 b3[4][4];
  #pragma unroll
  for (int kt=0; kt<4; ++kt)
    #pragma unroll
    for (int j=0; j<4; ++j)
      b3[kt][j] = *(const bf16x8*)(wsb + 14336 + (((kt*16 + w*4 + j)*64 + l)<<3));

  // ---- prologue: sidx + q1s for all QPB queries ----
  for (int e = tid; e < QPB*64; e += 256) {
    int qq = e>>6, t = e&63;
    int fp = fps_inds[q0+qq];
    sidx[qq][t] = gsidx[(q0+qq)*64 + t];
    q1s[qq][t] = xb[fp*3]*w0[t] + xb[fp*3+1]*w0[64+t] + xb[fp*3+2]*w0[128+t];
  }
  if (tid < QPB*3) {
    int qq = tid/3, c = tid - qq*3;
    int fp = fps_inds[q0+qq];
    out[(q0+qq)*3 + c] = xb[fp*3+c];
  }
  __syncthreads();

  const short* px1b = px1 + (size_t)b*NN*64;
  const int myrow = w*16 + lr;

  // prefetch first query's px1 row
  bf16x8 v0, v1;
  {
    int idx = sidx[0][myrow];
    v0 = *(const bf16x8*)(px1b + idx*64 + grp*8);
    v1 = *(const bf16x8*)(px1b + idx*64 + 32 + grp*8);
  }

  f32x4 zero4 = {0.f,0.f,0.f,0.f};

  for (int qq = 0; qq < QPB; ++qq) {
    const int p = qq & 1;

    // h1 row (wave-private): relu(PX1[idx] - Q1)
    bf16x8 a20, a21;
    #pragma unroll
    for (int j=0;j<8;++j) {
      a20[j] = f2bf(fmaxf(bf2f(v0[j]) - q1s[qq][grp*8+j], 0.f));
      a21[j] = f2bf(fmaxf(bf2f(v1[j]) - q1s[qq][32+grp*8+j], 0.f));
    }
    // prefetch next query's row (hides under layers 2+3)
    if (qq+1 < QPB) {
      int idx = sidx[qq+1][myrow];
      v0 = *(const bf16x8*)(px1b + idx*64 + grp*8);
      v1 = *(const bf16x8*)(px1b + idx*64 + 32 + grp*8);
    }

    // layer 2: wave-private 16 rows x all 8 ntiles; B via global (wf1 is L1-resident)
    #pragma unroll
    for (int nt=0; nt<8; ++nt) {
      f32x4 acc = zero4;
      bf16x8 w10 = *(const bf16x8*)(wsb + 6144 + (((0*8+nt)*64 + l)<<3));
      bf16x8 w11 = *(const bf16x8*)(wsb + 6144 + (((1*8+nt)*64 + l)<<3));
      acc = __builtin_amdgcn_mfma_f32_16x16x32_bf16(a20, w10, acc, 0,0,0);
      acc = __builtin_amdgcn_mfma_f32_16x16x32_bf16(a21, w11, acc, 0,0,0);
      #pragma unroll
      for (int i=0;i<4;++i)
        h2[p][w*16 + grp*4 + i][nt*16 + lr] = f2bf(fmaxf(acc[i], 0.f));
    }
    __syncthreads();   // only barrier per query (double-buffered h2)

    // layer 3: all 64 rows x wave's 4 ntiles; A from LDS (read once), B from regs
    f32x4 acc3[4][4];
    #pragma unroll
    for (int mt=0; mt<4; ++mt)
      #pragma unroll
      for (int j=0; j<4; ++j) acc3[mt][j] = zero4;
    #pragma unroll
    for (int kt=0; kt<4; ++kt)
      #pragma unroll
      for (int mt=0; mt<4; ++mt) {
        bf16x8 a = *(const bf16x8*)&h2[p][mt*16 + lr][kt*32 + grp*8];
        #pragma unroll
        for (int j=0; j<4; ++j)
          acc3[mt][j] = __builtin_amdgcn_mfma_f32_16x16x32_bf16(a, b3[kt][j], acc3[mt][j], 0,0,0);
      }
    #pragma unroll
    for (int j=0; j<4; ++j) {
      float m = 0.f;   // relu folded into maxpool
      #pragma unroll
      for (int mt=0; mt<4; ++mt)
        #pragma unroll
        for (int i=0; i<4; ++i) m = fmaxf(m, acc3[mt][j][i]);
      m = fmaxf(m, __shfl_xor(m, 16, 64));
      m = fmaxf(m, __shfl_xor(m, 32, 64));
      if (grp == 0) out[OUT_PTS_OFF + (q0+qq)*256 + (w*4+j)*16 + lr] = m;
    }
  }
}

extern "C" void kernel_launch(void* const* d_in, const int* in_sizes, int n_in,
                              void* d_out, int out_size, void* d_ws, size_t ws_size,
                              hipStream_t stream) {
  const float* xyz      = (const float*)d_in[0];
  const float* points   = (const float*)d_in[1];
  const int*   fps_inds = (const int*)d_in[2];
  const float* w0       = (const float*)d_in[3];
  const float* w1       = (const float*)d_in[4];
  const float* w2       = (const float*)d_in[5];
  float* out = (float*)d_out;

  int*   gsidx = (int*)d_ws;
  short* px1   = (short*)d_ws + WS_PX1_SH;
  short* wsb   = (short*)d_ws + WS_WF_SH;

  hipLaunchKernelGGL(prep_weights, dim3(184), dim3(256), 0, stream, w0, w1, w2, wsb);
  hipLaunchKernelGGL(px1_kernel,   dim3(512), dim3(256), 0, stream, xyz, points, wsb, px1);
  hipLaunchKernelGGL(select_kernel,dim3(NB*NS), dim3(256), 0, stream, xyz, fps_inds, gsidx, out);
  hipLaunchKernelGGL(mlp_kernel,   dim3(NB*NS/QPB), dim3(256), 0, stream,
                     xyz, fps_inds, w0, wsb, px1, gsidx, out);
}